// Round 2
// baseline (2753.657 us; speedup 1.0000x reference)
//
#include <hip/hip_runtime.h>
#include <hip/hip_bf16.h>

#define N_NODES 100000
#define N_EDGES 400000
#define N_GRAPHS 4096
#define BN_EPS 1e-5f

// ---------------- utility kernels ----------------
__global__ void k_copy_f32(float* __restrict__ dst, const float* __restrict__ src, int n) {
    int i = blockIdx.x * blockDim.x + threadIdx.x;
    if (i < n) dst[i] = src[i];
}

__global__ void k_zero_f32(float* __restrict__ dst, int n) {
    int i = blockIdx.x * blockDim.x + threadIdx.x;
    if (i < n) dst[i] = 0.f;
}

// ---------------- scatter-add (GIN aggregation) ----------------
// t[dst[e]][c] += h[src[e]][c]   (t pre-initialized with h, giving t = h + agg)
__global__ void k_scatter_f32(const float* __restrict__ h, const int* __restrict__ src,
                              const int* __restrict__ dst, float* __restrict__ t, int D) {
    int e = blockIdx.x;
    int s = src[e], d = dst[e];
    const float* hs = h + (long)s * D;
    float* td = t + (long)d * D;
    for (int c = threadIdx.x; c < D; c += blockDim.x)
        atomicAdd(&td[c], hs[c]);
}

// ---------------- GEMM: C[M x Kn] = act(A[M x Kd] @ B[Kd x Kn] + bias) ----------------
// A fp32 row-major, B fp32 row-major, bias fp32, C fp32. Kn must be a multiple of 64.
#define BM 64
#define BNN 64
#define BKK 16

__global__ __launch_bounds__(256) void k_gemm(const float* __restrict__ A,
                                              const float* __restrict__ B,
                                              const float* __restrict__ bias,
                                              float* __restrict__ C,
                                              int M, int Kd, int Kn, int relu) {
    __shared__ float As[BM][BKK + 1];
    __shared__ float Bs[BKK][BNN];
    int tid = threadIdx.x;
    int tx = tid & 15, ty = tid >> 4;
    int rowBase = blockIdx.x * BM;
    int colBase = blockIdx.y * BNN;
    float acc[4][4] = {};

    for (int k0 = 0; k0 < Kd; k0 += BKK) {
#pragma unroll
        for (int i = 0; i < 4; i++) {
            int idx = tid + i * 256;
            int r = idx >> 4;
            int k = idx & 15;
            int gr = rowBase + r, gk = k0 + k;
            As[r][k] = (gr < M && gk < Kd) ? A[(long)gr * Kd + gk] : 0.f;
        }
#pragma unroll
        for (int i = 0; i < 4; i++) {
            int idx = tid + i * 256;
            int k = idx >> 6;
            int c = idx & 63;
            int gk = k0 + k;
            Bs[k][c] = (gk < Kd) ? B[(long)gk * Kn + colBase + c] : 0.f;
        }
        __syncthreads();
#pragma unroll
        for (int kk = 0; kk < BKK; kk++) {
            float a[4], b[4];
#pragma unroll
            for (int i = 0; i < 4; i++) a[i] = As[ty * 4 + i][kk];
#pragma unroll
            for (int j = 0; j < 4; j++) b[j] = Bs[kk][tx * 4 + j];
#pragma unroll
            for (int i = 0; i < 4; i++)
#pragma unroll
                for (int j = 0; j < 4; j++)
                    acc[i][j] += a[i] * b[j];
        }
        __syncthreads();
    }

#pragma unroll
    for (int i = 0; i < 4; i++) {
        int gr = rowBase + ty * 4 + i;
        if (gr >= M) continue;
#pragma unroll
        for (int j = 0; j < 4; j++) {
            int gc = colBase + tx * 4 + j;
            float v = acc[i][j] + bias[gc];
            if (relu) v = fmaxf(v, 0.f);
            C[(long)gr * Kn + gc] = v;
        }
    }
}

// ---------------- BatchNorm ----------------
// stats[0..K) = sum, stats[K..2K) = sumsq  (K is a power of 2, <= 256)
__global__ void k_bn_accum(const float* __restrict__ h, float* __restrict__ stats, int N, int K) {
    int tid = threadIdx.x;
    int c = tid & (K - 1);
    int rpb = blockDim.x / K;
    int rowOff = tid / K;
    float s = 0.f, s2 = 0.f;
    for (int r = blockIdx.x * rpb + rowOff; r < N; r += gridDim.x * rpb) {
        float v = h[(long)r * K + c];
        s += v;
        s2 += v * v;
    }
    atomicAdd(&stats[c], s);
    atomicAdd(&stats[K + c], s2);
}

__global__ void k_bn_apply(float* __restrict__ h, const float* __restrict__ stats,
                           const float* __restrict__ gamma, const float* __restrict__ beta,
                           int N, int K) {
    int idx = blockIdx.x * blockDim.x + threadIdx.x;
    if (idx >= N * K) return;
    int c = idx & (K - 1);
    float invN = 1.0f / (float)N;
    float mu = stats[c] * invN;
    float var = stats[K + c] * invN - mu * mu;
    var = fmaxf(var, 0.f);
    float sc = rsqrtf(var + BN_EPS) * gamma[c];
    h[idx] = (h[idx] - mu) * sc + beta[c];
}

// ---------------- global add pool (K = 64) ----------------
__global__ void k_pool(const float* __restrict__ h, const int* __restrict__ batch,
                       float* __restrict__ pooled, int N) {
    int idx = blockIdx.x * blockDim.x + threadIdx.x;
    int r = idx >> 6;
    int c = idx & 63;
    if (r < N) atomicAdd(&pooled[batch[r] * 64 + c], h[idx]);
}

// ---------------- head: relu(relu(pooled @ Wf1 + bf1) @ Wf2 + bf2) ----------------
__global__ void k_head(const float* __restrict__ pooled, const float* __restrict__ Wf1,
                       const float* __restrict__ bf1, const float* __restrict__ Wf2,
                       const float* __restrict__ bf2, float* __restrict__ out) {
    int g = blockIdx.x * blockDim.x + threadIdx.x;
    if (g >= N_GRAPHS) return;
    const float* p = pooled + g * 64;
    float o = 0.f;
#pragma unroll
    for (int k = 0; k < 16; k++) {
        float s = bf1[k];
        for (int c = 0; c < 64; c++) s += p[c] * Wf1[c * 16 + k];
        s = fmaxf(s, 0.f);
        o += s * Wf2[k];
    }
    o += bf2[0];
    o = fmaxf(o, 0.f);
    out[g] = o;
}

// ---------------- launch ----------------
static inline dim3 gemm_grid(int M, int Kn) {
    return dim3((M + BM - 1) / BM, Kn / BNN);
}

extern "C" void kernel_launch(void* const* d_in, const int* in_sizes, int n_in,
                              void* d_out, int out_size, void* d_ws, size_t ws_size,
                              hipStream_t stream) {
    const float* x    = (const float*)d_in[0];
    const int*  ei    = (const int*)d_in[1];
    const int*  batch = (const int*)d_in[2];
    const float* W1a = (const float*)d_in[3];
    const float* b1a = (const float*)d_in[4];
    const float* W1b = (const float*)d_in[5];
    const float* b1b = (const float*)d_in[6];
    const float* g1  = (const float*)d_in[7];
    const float* be1 = (const float*)d_in[8];
    const float* W2a = (const float*)d_in[9];
    const float* b2a = (const float*)d_in[10];
    const float* W2b = (const float*)d_in[11];
    const float* b2b = (const float*)d_in[12];
    const float* g2  = (const float*)d_in[13];
    const float* be2 = (const float*)d_in[14];
    const float* W3a = (const float*)d_in[15];
    const float* b3a = (const float*)d_in[16];
    const float* W3b = (const float*)d_in[17];
    const float* b3b = (const float*)d_in[18];
    const float* g3  = (const float*)d_in[19];
    const float* be3 = (const float*)d_in[20];
    const float* Wf1 = (const float*)d_in[21];
    const float* bf1 = (const float*)d_in[22];
    const float* Wf2 = (const float*)d_in[23];
    const float* bf2 = (const float*)d_in[24];

    const int N = N_NODES, E = N_EDGES;
    const int* src = ei;
    const int* dst = ei + E;

    // workspace layout (fp32), ping-pong buffers:
    //   bufA: N * 373 floats (max-dim buffer)
    //   bufB: N * 256 floats
    //   stats: 512 floats, pooled: N_GRAPHS * 64 floats
    float* bufA   = (float*)d_ws;
    float* bufB   = bufA + (size_t)N * 373;
    float* stats  = bufB + (size_t)N * 256;
    float* pooled = stats + 512;

    // ---------- layer 1 (373 -> 256 -> 256) ----------
    {
        int D = 373, Dh = 256;
        int n = N * D;
        k_copy_f32<<<(n + 255) / 256, 256, 0, stream>>>(bufA, x, n);
        k_scatter_f32<<<E, 256, 0, stream>>>(x, src, dst, bufA, D);
        k_gemm<<<gemm_grid(N, Dh), 256, 0, stream>>>(bufA, W1a, b1a, bufB, N, D, Dh, 1);
        k_gemm<<<gemm_grid(N, Dh), 256, 0, stream>>>(bufB, W1b, b1b, bufA, N, Dh, Dh, 1);
        k_zero_f32<<<2, 256, 0, stream>>>(stats, 512);
        k_bn_accum<<<256, 256, 0, stream>>>(bufA, stats, N, Dh);
        k_bn_apply<<<((N * Dh) + 255) / 256, 256, 0, stream>>>(bufA, stats, g1, be1, N, Dh);
    }
    // ---------- layer 2 (256 -> 128 -> 128) ----------
    {
        int D = 256, Dh = 128;
        int n = N * D;
        k_copy_f32<<<(n + 255) / 256, 256, 0, stream>>>(bufB, bufA, n);
        k_scatter_f32<<<E, 256, 0, stream>>>(bufA, src, dst, bufB, D);
        k_gemm<<<gemm_grid(N, Dh), 256, 0, stream>>>(bufB, W2a, b2a, bufA, N, D, Dh, 1);
        k_gemm<<<gemm_grid(N, Dh), 256, 0, stream>>>(bufA, W2b, b2b, bufB, N, Dh, Dh, 1);
        k_zero_f32<<<2, 256, 0, stream>>>(stats, 512);
        k_bn_accum<<<256, 256, 0, stream>>>(bufB, stats, N, Dh);
        k_bn_apply<<<((N * Dh) + 255) / 256, 256, 0, stream>>>(bufB, stats, g2, be2, N, Dh);
    }
    // ---------- layer 3 (128 -> 64 -> 64) ----------
    {
        int D = 128, Dh = 64;
        int n = N * D;
        k_copy_f32<<<(n + 255) / 256, 256, 0, stream>>>(bufA, bufB, n);
        k_scatter_f32<<<E, 128, 0, stream>>>(bufB, src, dst, bufA, D);
        k_gemm<<<gemm_grid(N, Dh), 256, 0, stream>>>(bufA, W3a, b3a, bufB, N, D, Dh, 1);
        k_gemm<<<gemm_grid(N, Dh), 256, 0, stream>>>(bufB, W3b, b3b, bufA, N, Dh, Dh, 1);
        k_zero_f32<<<2, 256, 0, stream>>>(stats, 512);
        k_bn_accum<<<256, 256, 0, stream>>>(bufA, stats, N, Dh);
        k_bn_apply<<<((N * Dh) + 255) / 256, 256, 0, stream>>>(bufA, stats, g3, be3, N, Dh);
    }
    // ---------- pool + head ----------
    k_zero_f32<<<(N_GRAPHS * 64 + 255) / 256, 256, 0, stream>>>(pooled, N_GRAPHS * 64);
    k_pool<<<((N * 64) + 255) / 256, 256, 0, stream>>>(bufA, batch, pooled, N);
    k_head<<<(N_GRAPHS + 255) / 256, 256, 0, stream>>>(pooled, Wf1, bf1, Wf2, bf2, (float*)d_out);
}

// Round 3
// 2082.271 us; speedup vs baseline: 1.3224x; 1.3224x over previous
//
#include <hip/hip_runtime.h>
#include <hip/hip_bf16.h>

#define N_NODES 100000
#define N_EDGES 400000
#define N_GRAPHS 4096
#define BN_EPS 1e-5f

// ---------------- utility kernels ----------------
__global__ void k_copy_f32(float* __restrict__ dst, const float* __restrict__ src, int n) {
    int i = blockIdx.x * blockDim.x + threadIdx.x;
    if (i < n) dst[i] = src[i];
}

__global__ void k_zero_f32(float* __restrict__ dst, int n) {
    int i = blockIdx.x * blockDim.x + threadIdx.x;
    if (i < n) dst[i] = 0.f;
}

// ---------------- scatter-add: t[dst[e]][c] += h[src[e]][c], D = 1<<LOGD ----------------
template<int LOGD>
__global__ void k_scatter(const float* __restrict__ h, const int* __restrict__ src,
                          const int* __restrict__ dst, float* __restrict__ t) {
    const int D = 1 << LOGD;
    int idx = blockIdx.x * blockDim.x + threadIdx.x;
    int e = idx >> LOGD;
    int c = idx & (D - 1);
    if (e < N_EDGES) {
        int s = src[e], d = dst[e];
        atomicAdd(&t[(long)d * D + c], h[(long)s * D + c]);
    }
}

// ---------------- GEMM: C[M x N] = epi(pre(A)[M x K] @ B[K x N]) ----------------
// preMode: 0 = none, 1 = relu(a + p1[k]), 2 = a*p1[k] + p2[k]   (applied to A elements)
// epiRelu: 0 = C=acc, 1 = C=relu(acc + bias[col])
#define TBM 128
#define TBN 64
#define TBK 16

__global__ __launch_bounds__(256) void k_gemm(const float* __restrict__ A,
                                              const float* __restrict__ B,
                                              const float* __restrict__ p1,
                                              const float* __restrict__ p2,
                                              const float* __restrict__ bias,
                                              float* __restrict__ C,
                                              int M, int K, int N,
                                              int preMode, int epiRelu) {
    __shared__ float As[TBK][TBM + 4];   // transposed: [k][row]
    __shared__ float Bs[TBK][TBN];
    int tid = threadIdx.x;
    int tx = tid & 15, ty = tid >> 4;
    long rowBase = (long)blockIdx.x * TBM;
    int colBase = blockIdx.y * TBN;
    float acc[8][4] = {};
    const bool k4 = (K & 3) == 0;

    for (int k0 = 0; k0 < K; k0 += TBK) {
        // ---- stage A (128x16) ----
        if (k4) {
#pragma unroll
            for (int i = 0; i < 2; i++) {
                int f = tid + i * 256;           // 512 float4 slots
                int r = f >> 2;
                int kq = (f & 3) * 4;
                long gr = rowBase + r;
                float4 v = make_float4(0.f, 0.f, 0.f, 0.f);
                if (gr < M) v = *(const float4*)(A + gr * K + k0 + kq);
                float e[4] = {v.x, v.y, v.z, v.w};
                if (preMode == 1) {
#pragma unroll
                    for (int j = 0; j < 4; j++) e[j] = fmaxf(e[j] + p1[k0 + kq + j], 0.f);
                } else if (preMode == 2) {
#pragma unroll
                    for (int j = 0; j < 4; j++) e[j] = e[j] * p1[k0 + kq + j] + p2[k0 + kq + j];
                }
#pragma unroll
                for (int j = 0; j < 4; j++) As[kq + j][r] = e[j];
            }
        } else {
#pragma unroll
            for (int i = 0; i < 8; i++) {
                int idx = tid + i * 256;         // 2048 scalar slots
                int r = idx >> 4;
                int k = idx & 15;
                long gr = rowBase + r;
                int gk = k0 + k;
                float v = 0.f;
                if (gr < M && gk < K) v = A[gr * K + gk];
                if (preMode == 1) v = fmaxf(v + p1[gk < K ? gk : 0], 0.f);
                else if (preMode == 2) v = v * p1[gk < K ? gk : 0] + p2[gk < K ? gk : 0];
                As[k][r] = v;
            }
        }
        // ---- stage B (16x64) ----
        {
            int kk = tid >> 4;
            int n4 = (tid & 15) * 4;
            int gk = k0 + kk;
            float4 v = make_float4(0.f, 0.f, 0.f, 0.f);
            if (gk < K) v = *(const float4*)(B + (long)gk * N + colBase + n4);
            *(float4*)&Bs[kk][n4] = v;
        }
        __syncthreads();
        // ---- compute ----
#pragma unroll
        for (int kk = 0; kk < TBK; kk++) {
            float a[8], b[4];
#pragma unroll
            for (int i = 0; i < 8; i++) a[i] = As[kk][ty * 8 + i];
#pragma unroll
            for (int j = 0; j < 4; j++) b[j] = Bs[kk][tx * 4 + j];
#pragma unroll
            for (int i = 0; i < 8; i++)
#pragma unroll
                for (int j = 0; j < 4; j++)
                    acc[i][j] += a[i] * b[j];
        }
        __syncthreads();
    }

    // ---- epilogue ----
#pragma unroll
    for (int i = 0; i < 8; i++) {
        long gr = rowBase + ty * 8 + i;
        if (gr >= M) continue;
        int gc = colBase + tx * 4;
        float4 v = make_float4(acc[i][0], acc[i][1], acc[i][2], acc[i][3]);
        if (epiRelu) {
            v.x = fmaxf(v.x + bias[gc + 0], 0.f);
            v.y = fmaxf(v.y + bias[gc + 1], 0.f);
            v.z = fmaxf(v.z + bias[gc + 2], 0.f);
            v.w = fmaxf(v.w + bias[gc + 3], 0.f);
        }
        *(float4*)(C + gr * N + gc) = v;
    }
}

// ---------------- BatchNorm stats ----------------
__global__ void k_bn_accum(const float* __restrict__ h, float* __restrict__ stats, int N, int K) {
    int tid = threadIdx.x;
    int c = tid & (K - 1);
    int rpb = blockDim.x / K;
    int rowOff = tid / K;
    float s = 0.f, s2 = 0.f;
    for (int r = blockIdx.x * rpb + rowOff; r < N; r += gridDim.x * rpb) {
        float v = h[(long)r * K + c];
        s += v;
        s2 += v * v;
    }
    atomicAdd(&stats[c], s);
    atomicAdd(&stats[K + c], s2);
}

// scsh[0..K) = scale, scsh[K..2K) = shift
__global__ void k_bn_finalize(const float* __restrict__ stats, const float* __restrict__ gamma,
                              const float* __restrict__ beta, float* __restrict__ scsh, int K) {
    int c = threadIdx.x;
    if (c < K) {
        float invN = 1.0f / (float)N_NODES;
        float mu = stats[c] * invN;
        float var = fmaxf(stats[K + c] * invN - mu * mu, 0.f);
        float sc = rsqrtf(var + BN_EPS) * gamma[c];
        scsh[c] = sc;
        scsh[K + c] = beta[c] - mu * sc;
    }
}

// ---------------- global add pool with fused BN affine (K = 64) ----------------
__global__ void k_pool(const float* __restrict__ h, const int* __restrict__ batch,
                       const float* __restrict__ scsh, float* __restrict__ pooled, int N) {
    int idx = blockIdx.x * blockDim.x + threadIdx.x;
    int r = idx >> 6;
    int c = idx & 63;
    if (r < N) {
        float v = h[idx] * scsh[c] + scsh[64 + c];
        atomicAdd(&pooled[batch[r] * 64 + c], v);
    }
}

// ---------------- head ----------------
__global__ void k_head(const float* __restrict__ pooled, const float* __restrict__ Wf1,
                       const float* __restrict__ bf1, const float* __restrict__ Wf2,
                       const float* __restrict__ bf2, float* __restrict__ out) {
    int g = blockIdx.x * blockDim.x + threadIdx.x;
    if (g >= N_GRAPHS) return;
    const float* p = pooled + g * 64;
    float o = 0.f;
#pragma unroll
    for (int k = 0; k < 16; k++) {
        float s = bf1[k];
        for (int c = 0; c < 64; c++) s += p[c] * Wf1[c * 16 + k];
        s = fmaxf(s, 0.f);
        o += s * Wf2[k];
    }
    o += bf2[0];
    o = fmaxf(o, 0.f);
    out[g] = o;
}

// ---------------- launch ----------------
extern "C" void kernel_launch(void* const* d_in, const int* in_sizes, int n_in,
                              void* d_out, int out_size, void* d_ws, size_t ws_size,
                              hipStream_t stream) {
    const float* x    = (const float*)d_in[0];
    const int*  ei    = (const int*)d_in[1];
    const int*  batch = (const int*)d_in[2];
    const float* W1a = (const float*)d_in[3];
    const float* b1a = (const float*)d_in[4];
    const float* W1b = (const float*)d_in[5];
    const float* b1b = (const float*)d_in[6];
    const float* g1  = (const float*)d_in[7];
    const float* be1 = (const float*)d_in[8];
    const float* W2a = (const float*)d_in[9];
    const float* b2a = (const float*)d_in[10];
    const float* W2b = (const float*)d_in[11];
    const float* b2b = (const float*)d_in[12];
    const float* g2  = (const float*)d_in[13];
    const float* be2 = (const float*)d_in[14];
    const float* W3a = (const float*)d_in[15];
    const float* b3a = (const float*)d_in[16];
    const float* W3b = (const float*)d_in[17];
    const float* b3b = (const float*)d_in[18];
    const float* g3  = (const float*)d_in[19];
    const float* be3 = (const float*)d_in[20];
    const float* Wf1 = (const float*)d_in[21];
    const float* bf1 = (const float*)d_in[22];
    const float* Wf2 = (const float*)d_in[23];
    const float* bf2 = (const float*)d_in[24];

    const int N = N_NODES, E = N_EDGES;
    const int* src = ei;
    const int* dst = ei + E;

    // workspace: two N*256 ping-pong buffers + stats + scsh + pooled
    float* bufY   = (float*)d_ws;              // N * 256
    float* bufT   = bufY + (size_t)N * 256;    // N * 256
    float* stats  = bufT + (size_t)N * 256;    // 512
    float* scsh   = stats + 512;               // 512
    float* pooled = scsh + 512;                // N_GRAPHS * 64

    dim3 blk(256);
    int gx = (N + TBM - 1) / TBM;              // 782

    // ---------- layer 1: y1 = x@W1a (K=373); t1 = y1 + scatter(y1); r1 = relu(relu(t1+b1a)@W1b + b1b)
    k_gemm<<<dim3(gx, 4), blk, 0, stream>>>(x, W1a, nullptr, nullptr, nullptr, bufY, N, 373, 256, 0, 0);
    k_copy_f32<<<(N * 256 + 255) / 256, blk, 0, stream>>>(bufT, bufY, N * 256);
    k_scatter<8><<<(E * 256) / 256, blk, 0, stream>>>(bufY, src, dst, bufT);
    k_gemm<<<dim3(gx, 4), blk, 0, stream>>>(bufT, W1b, b1a, nullptr, b1b, bufY, N, 256, 256, 1, 1);
    k_zero_f32<<<2, blk, 0, stream>>>(stats, 512);
    k_bn_accum<<<256, blk, 0, stream>>>(bufY, stats, N, 256);
    k_bn_finalize<<<1, blk, 0, stream>>>(stats, g1, be1, scsh, 256);

    // ---------- layer 2: y2 = bn(r1)@W2a (BN fused in A-load); scatter in 128-dim
    k_gemm<<<dim3(gx, 2), blk, 0, stream>>>(bufY, W2a, scsh, scsh + 256, nullptr, bufT, N, 256, 128, 2, 0);
    k_copy_f32<<<(N * 128 + 255) / 256, blk, 0, stream>>>(bufY, bufT, N * 128);
    k_scatter<7><<<(E * 128) / 256, blk, 0, stream>>>(bufT, src, dst, bufY);
    k_gemm<<<dim3(gx, 2), blk, 0, stream>>>(bufY, W2b, b2a, nullptr, b2b, bufT, N, 128, 128, 1, 1);
    k_zero_f32<<<2, blk, 0, stream>>>(stats, 512);
    k_bn_accum<<<256, blk, 0, stream>>>(bufT, stats, N, 128);
    k_bn_finalize<<<1, blk, 0, stream>>>(stats, g2, be2, scsh, 128);

    // ---------- layer 3: y3 = bn(r2)@W3a; scatter in 64-dim
    k_gemm<<<dim3(gx, 1), blk, 0, stream>>>(bufT, W3a, scsh, scsh + 128, nullptr, bufY, N, 128, 64, 2, 0);
    k_copy_f32<<<(N * 64 + 255) / 256, blk, 0, stream>>>(bufT, bufY, N * 64);
    k_scatter<6><<<(E * 64) / 256, blk, 0, stream>>>(bufY, src, dst, bufT);
    k_gemm<<<dim3(gx, 1), blk, 0, stream>>>(bufT, W3b, b3a, nullptr, b3b, bufY, N, 64, 64, 1, 1);
    k_zero_f32<<<2, blk, 0, stream>>>(stats, 512);
    k_bn_accum<<<256, blk, 0, stream>>>(bufY, stats, N, 64);
    k_bn_finalize<<<1, blk, 0, stream>>>(stats, g3, be3, scsh, 64);

    // ---------- pool (BN affine fused) + head
    k_zero_f32<<<(N_GRAPHS * 64 + 255) / 256, blk, 0, stream>>>(pooled, N_GRAPHS * 64);
    k_pool<<<((N * 64) + 255) / 256, blk, 0, stream>>>(bufY, batch, scsh, pooled, N);
    k_head<<<(N_GRAPHS + 255) / 256, blk, 0, stream>>>(pooled, Wf1, bf1, Wf2, bf2, (float*)d_out);
}

// Round 4
// 1187.605 us; speedup vs baseline: 2.3187x; 1.7533x over previous
//
#include <hip/hip_runtime.h>

#define N_NODES 100000
#define N_EDGES 400000
#define N_GRAPHS 4096
#define BN_EPS 1e-5f
#define DEG_CAP 96

typedef unsigned short ushort_t;
typedef short short8 __attribute__((ext_vector_type(8)));
typedef float floatx4 __attribute__((ext_vector_type(4)));

__device__ __forceinline__ ushort_t f2b(float f) {
    union { float f; unsigned u; } v; v.f = f;
    unsigned r = v.u + 0x7fffu + ((v.u >> 16) & 1u);
    return (ushort_t)(r >> 16);
}
__device__ __forceinline__ float b2f(ushort_t b) {
    union { unsigned u; float f; } v; v.u = ((unsigned)b) << 16;
    return v.f;
}

// ---------------- pad + convert x: [N][373] f32 -> [N][384] bf16 ----------------
__global__ void k_pad_x(const float* __restrict__ x, ushort_t* __restrict__ xb) {
    int n = blockIdx.x;
    const float* xr = x + (long)n * 373;
    ushort_t* o = xb + (long)n * 384;
    for (int j = threadIdx.x; j < 384; j += 128)
        o[j] = (j < 373) ? f2b(xr[j]) : (ushort_t)0;
}

// ---------------- utility ----------------
__global__ void k_zero_int(int* __restrict__ p, int n) {
    int i = blockIdx.x * blockDim.x + threadIdx.x;
    if (i < n) p[i] = 0;
}
__global__ void k_zero_f32(float* __restrict__ p, int n) {
    int i = blockIdx.x * blockDim.x + threadIdx.x;
    if (i < n) p[i] = 0.f;
}

// ---------------- bucketed in-edge lists (no atomic fp, no sort) ----------------
__global__ void k_fill(const int* __restrict__ src, const int* __restrict__ dst,
                       int* __restrict__ cursor, int* __restrict__ elist) {
    int e = blockIdx.x * blockDim.x + threadIdx.x;
    if (e < N_EDGES) {
        int d = dst[e];
        int slot = atomicAdd(&cursor[d], 1);
        if (slot < DEG_CAP) elist[(long)d * DEG_CAP + slot] = src[e];
    }
}

// ---------------- weight prep: BT[n][k] = bf16(W[k][n] * sc[k]), K-padded ----------------
__global__ void k_prep_bt(const float* __restrict__ W, const float* __restrict__ sc,
                          ushort_t* __restrict__ BT, int K, int Kp, int Nn) {
    int k = blockIdx.x * 128 + threadIdx.x;
    int n = blockIdx.y;
    if (k >= Kp) return;
    float v = 0.f;
    if (k < K) { v = W[(long)k * Nn + n]; if (sc) v *= sc[k]; }
    BT[(long)n * Kp + k] = f2b(v);
}

// biasEff[n] = sum_k sh[k] * W[k][n]
__global__ void k_bias_eff(const float* __restrict__ W, const float* __restrict__ sh,
                           float* __restrict__ out, int K, int Nn) {
    int n = blockIdx.x * blockDim.x + threadIdx.x;
    if (n >= Nn) return;
    float s = 0.f;
    for (int k = 0; k < K; k++) s += sh[k] * W[(long)k * Nn + n];
    out[n] = s;
}

// ---------------- MFMA GEMM: C[M][Nn] = epi(A[M][Kp] @ BT^T), bf16 in/out, fp32 acc ----
// Block 128x64, 256 threads (4 waves, each 32 rows x 64 cols via 2x4 16x16x32 MFMAs).
// A staged via global_load_lds in fragment order; BT fragments loaded direct from global.
__global__ __launch_bounds__(256) void k_gemm(const ushort_t* __restrict__ A,
                                              const ushort_t* __restrict__ BT,
                                              const float* __restrict__ bias,
                                              ushort_t* __restrict__ C,
                                              int M, int Kp, int Nn, int relu) {
    __shared__ __align__(16) ushort_t As[128 * 32];   // 8 KB, fragment-order 16B slots
    const int tid = threadIdx.x;
    const int wave = tid >> 6, lane = tid & 63;
    const int ln = lane & 15, kg = lane >> 4;
    const long rowBase = (long)blockIdx.x * 128;
    const int colBase = blockIdx.y * 64;

    // staging: thread tid owns slots tid and tid+256
    // slot s: row = (s>>6)*16 + (s&15), k-group = (s>>4)&3
    int rr = tid & 15;
    int ko = ((tid >> 4) & 3) * 8;
    long row0 = rowBase + ((tid >> 6) << 4) + rr;
    long row1 = row0 + 64;
    if (row0 >= M) row0 = M - 1;
    if (row1 >= M) row1 = M - 1;
    const ushort_t* ap0 = A + row0 * Kp + ko;
    const ushort_t* ap1 = A + row1 * Kp + ko;
    ushort_t* ld0 = &As[wave * 512];          // wave-uniform LDS base (lane*16 implicit)
    ushort_t* ld1 = &As[2048 + wave * 512];

    const ushort_t* bp = BT + (long)(colBase + ln) * Kp + kg * 8;

    floatx4 acc[2][4];
#pragma unroll
    for (int i = 0; i < 2; i++)
#pragma unroll
        for (int j = 0; j < 4; j++) acc[i][j] = (floatx4){0.f, 0.f, 0.f, 0.f};

    for (int k0 = 0; k0 < Kp; k0 += 32) {
        __syncthreads();
        __builtin_amdgcn_global_load_lds((const __attribute__((address_space(1))) void*)ap0,
                                         (__attribute__((address_space(3))) void*)ld0, 16, 0, 0);
        __builtin_amdgcn_global_load_lds((const __attribute__((address_space(1))) void*)ap1,
                                         (__attribute__((address_space(3))) void*)ld1, 16, 0, 0);
        ap0 += 32; ap1 += 32;
        short8 bfr[4];
#pragma unroll
        for (int tn = 0; tn < 4; tn++)
            bfr[tn] = *(const short8*)(bp + (long)tn * 16 * Kp + k0);
        __syncthreads();   // drains vmcnt: LDS tile + B frags ready
        short8 afr[2];
#pragma unroll
        for (int mt = 0; mt < 2; mt++)
            afr[mt] = *(const short8*)&As[((wave * 2 + mt) * 64 + lane) * 8];
#pragma unroll
        for (int mt = 0; mt < 2; mt++)
#pragma unroll
            for (int tn = 0; tn < 4; tn++)
                acc[mt][tn] = __builtin_amdgcn_mfma_f32_16x16x32_bf16(afr[mt], bfr[tn], acc[mt][tn], 0, 0, 0);
    }

    // epilogue: C/D layout col=lane&15, row=(lane>>4)*4+reg
#pragma unroll
    for (int mt = 0; mt < 2; mt++) {
#pragma unroll
        for (int tn = 0; tn < 4; tn++) {
            int gc = colBase + tn * 16 + ln;
            float bv = bias ? bias[gc] : 0.f;
#pragma unroll
            for (int r = 0; r < 4; r++) {
                long gr = rowBase + wave * 32 + mt * 16 + kg * 4 + r;
                if (gr < M) {
                    float v = acc[mt][tn][r] + bv;
                    if (relu) v = fmaxf(v, 0.f);
                    C[gr * Nn + gc] = f2b(v);
                }
            }
        }
    }
}

// ---------------- gather-aggregate: out[n] = relu(y[n] + sum_nbr y[s] + badd) ----------
template<int D>
__global__ void k_aggregate(const ushort_t* __restrict__ y, const int* __restrict__ cursor,
                            const int* __restrict__ elist, const float* __restrict__ badd,
                            ushort_t* __restrict__ out) {
    int n = blockIdx.x;
    int c = threadIdx.x;
    int cnt = cursor[n];
    if (cnt > DEG_CAP) cnt = DEG_CAP;
    float t = b2f(y[(long)n * D + c]);
    const int* el = elist + (long)n * DEG_CAP;
    for (int i = 0; i < cnt; i++) {
        int s = el[i];
        t += b2f(y[(long)s * D + c]);
    }
    t = fmaxf(t + badd[c], 0.f);
    out[(long)n * D + c] = f2b(t);
}

// ---------------- BatchNorm stats (bf16 input) ----------------
__global__ void k_bn_accum(const ushort_t* __restrict__ h, float* __restrict__ stats, int N, int K) {
    int tid = threadIdx.x;
    int c = tid & (K - 1);
    int rpb = blockDim.x / K;
    int rowOff = tid / K;
    float s = 0.f, s2 = 0.f;
    for (int r = blockIdx.x * rpb + rowOff; r < N; r += gridDim.x * rpb) {
        float v = b2f(h[(long)r * K + c]);
        s += v; s2 += v * v;
    }
    atomicAdd(&stats[c], s);
    atomicAdd(&stats[K + c], s2);
}

// scsh[0..K) = scale, scsh[K..2K) = shift
__global__ void k_bn_finalize(const float* __restrict__ stats, const float* __restrict__ gamma,
                              const float* __restrict__ beta, float* __restrict__ scsh, int K) {
    int c = threadIdx.x;
    if (c < K) {
        float invN = 1.0f / (float)N_NODES;
        float mu = stats[c] * invN;
        float var = fmaxf(stats[K + c] * invN - mu * mu, 0.f);
        float sc = rsqrtf(var + BN_EPS) * gamma[c];
        scsh[c] = sc;
        scsh[K + c] = beta[c] - mu * sc;
    }
}

// ---------------- pool with fused BN affine (D=64) ----------------
__global__ void k_pool(const ushort_t* __restrict__ h, const int* __restrict__ batch,
                       const float* __restrict__ scsh, float* __restrict__ pooled) {
    int idx = blockIdx.x * blockDim.x + threadIdx.x;
    int r = idx >> 6, c = idx & 63;
    if (r < N_NODES) {
        float v = b2f(h[idx]) * scsh[c] + scsh[64 + c];
        atomicAdd(&pooled[batch[r] * 64 + c], v);
    }
}

// ---------------- head ----------------
__global__ void k_head(const float* __restrict__ pooled, const float* __restrict__ Wf1,
                       const float* __restrict__ bf1, const float* __restrict__ Wf2,
                       const float* __restrict__ bf2, float* __restrict__ out) {
    int g = blockIdx.x * blockDim.x + threadIdx.x;
    if (g >= N_GRAPHS) return;
    const float* p = pooled + g * 64;
    float o = 0.f;
#pragma unroll
    for (int k = 0; k < 16; k++) {
        float s = bf1[k];
        for (int c = 0; c < 64; c++) s += p[c] * Wf1[c * 16 + k];
        s = fmaxf(s, 0.f);
        o += s * Wf2[k];
    }
    o += bf2[0];
    o = fmaxf(o, 0.f);
    out[g] = o;
}

// ---------------- launch ----------------
extern "C" void kernel_launch(void* const* d_in, const int* in_sizes, int n_in,
                              void* d_out, int out_size, void* d_ws, size_t ws_size,
                              hipStream_t stream) {
    const float* x    = (const float*)d_in[0];
    const int*  ei    = (const int*)d_in[1];
    const int*  batch = (const int*)d_in[2];
    const float* W1a = (const float*)d_in[3];
    const float* b1a = (const float*)d_in[4];
    const float* W1b = (const float*)d_in[5];
    const float* b1b = (const float*)d_in[6];
    const float* g1  = (const float*)d_in[7];
    const float* be1 = (const float*)d_in[8];
    const float* W2a = (const float*)d_in[9];
    const float* b2a = (const float*)d_in[10];
    const float* W2b = (const float*)d_in[11];
    const float* b2b = (const float*)d_in[12];
    const float* g2  = (const float*)d_in[13];
    const float* be2 = (const float*)d_in[14];
    const float* W3a = (const float*)d_in[15];
    const float* b3a = (const float*)d_in[16];
    const float* W3b = (const float*)d_in[17];
    const float* b3b = (const float*)d_in[18];
    const float* g3  = (const float*)d_in[19];
    const float* be3 = (const float*)d_in[20];
    const float* Wf1 = (const float*)d_in[21];
    const float* bf1 = (const float*)d_in[22];
    const float* Wf2 = (const float*)d_in[23];
    const float* bf2 = (const float*)d_in[24];

    const int N = N_NODES, E = N_EDGES;
    const int* src = ei;
    const int* dst = ei + E;

    // ---- workspace carve (256B aligned) ----
    char* wp = (char*)d_ws;
    auto carve = [&](size_t bytes) {
        char* p = wp;
        wp += (bytes + 255) & ~(size_t)255;
        return (void*)p;
    };
    ushort_t* xb     = (ushort_t*)carve((size_t)N * 384 * 2);   // 76.8 MB
    ushort_t* bufA   = (ushort_t*)carve((size_t)N * 256 * 2);   // 51.2 MB
    ushort_t* bufB   = (ushort_t*)carve((size_t)N * 256 * 2);   // 51.2 MB
    int*      elist  = (int*)carve((size_t)N * DEG_CAP * 4);    // 38.4 MB
    int*      cursor = (int*)carve((size_t)N * 4);
    ushort_t* BT     = (ushort_t*)carve((size_t)256 * 384 * 2); // 196 KB (reused)
    float*    stats  = (float*)carve(512 * 4);
    float*    scsh   = (float*)carve(512 * 4);
    float*    biasE  = (float*)carve(256 * 4);
    float*    pooled = (float*)carve((size_t)N_GRAPHS * 64 * 4);

    dim3 blk(256);
    const int gx = (N + 127) / 128;   // 782

    // ---- prep: pad x, build in-edge buckets ----
    k_pad_x<<<N, 128, 0, stream>>>(x, xb);
    k_zero_int<<<(N + 255) / 256, blk, 0, stream>>>(cursor, N);
    k_fill<<<(E + 255) / 256, blk, 0, stream>>>(src, dst, cursor, elist);

    // ---------- layer 1: 373 -> 256 -> 256 ----------
    k_prep_bt<<<dim3(3, 256), 128, 0, stream>>>(W1a, nullptr, BT, 373, 384, 256);
    k_gemm<<<dim3(gx, 4), blk, 0, stream>>>(xb, BT, nullptr, bufA, N, 384, 256, 0);
    k_aggregate<256><<<N, 256, 0, stream>>>(bufA, cursor, elist, b1a, bufB);
    k_prep_bt<<<dim3(2, 256), 128, 0, stream>>>(W1b, nullptr, BT, 256, 256, 256);
    k_gemm<<<dim3(gx, 4), blk, 0, stream>>>(bufB, BT, b1b, bufA, N, 256, 256, 1);
    k_zero_f32<<<2, blk, 0, stream>>>(stats, 512);
    k_bn_accum<<<256, blk, 0, stream>>>(bufA, stats, N, 256);
    k_bn_finalize<<<1, blk, 0, stream>>>(stats, g1, be1, scsh, 256);

    // ---------- layer 2: 256 -> 128 -> 128 (BN folded into W2a + biasEff) ----------
    k_prep_bt<<<dim3(2, 128), 128, 0, stream>>>(W2a, scsh, BT, 256, 256, 128);
    k_bias_eff<<<1, 128, 0, stream>>>(W2a, scsh + 256, biasE, 256, 128);
    k_gemm<<<dim3(gx, 2), blk, 0, stream>>>(bufA, BT, biasE, bufB, N, 256, 128, 0);
    k_aggregate<128><<<N, 128, 0, stream>>>(bufB, cursor, elist, b2a, bufA);
    k_prep_bt<<<dim3(1, 128), 128, 0, stream>>>(W2b, nullptr, BT, 128, 128, 128);
    k_gemm<<<dim3(gx, 2), blk, 0, stream>>>(bufA, BT, b2b, bufB, N, 128, 128, 1);
    k_zero_f32<<<2, blk, 0, stream>>>(stats, 512);
    k_bn_accum<<<256, blk, 0, stream>>>(bufB, stats, N, 128);
    k_bn_finalize<<<1, blk, 0, stream>>>(stats, g2, be2, scsh, 128);

    // ---------- layer 3: 128 -> 64 -> 64 ----------
    k_prep_bt<<<dim3(1, 64), 128, 0, stream>>>(W3a, scsh, BT, 128, 128, 64);
    k_bias_eff<<<1, 64, 0, stream>>>(W3a, scsh + 128, biasE, 128, 64);
    k_gemm<<<dim3(gx, 1), blk, 0, stream>>>(bufB, BT, biasE, bufA, N, 128, 64, 0);
    k_aggregate<64><<<N, 64, 0, stream>>>(bufA, cursor, elist, b3a, bufB);
    k_prep_bt<<<dim3(1, 64), 128, 0, stream>>>(W3b, nullptr, BT, 64, 64, 64);
    k_gemm<<<dim3(gx, 1), blk, 0, stream>>>(bufB, BT, b3b, bufA, N, 64, 64, 1);
    k_zero_f32<<<2, blk, 0, stream>>>(stats, 512);
    k_bn_accum<<<256, blk, 0, stream>>>(bufA, stats, N, 64);
    k_bn_finalize<<<1, blk, 0, stream>>>(stats, g3, be3, scsh, 64);

    // ---------- pool (BN affine fused) + head ----------
    k_zero_f32<<<(N_GRAPHS * 64 + 255) / 256, blk, 0, stream>>>(pooled, N_GRAPHS * 64);
    k_pool<<<((N * 64) + 255) / 256, blk, 0, stream>>>(bufA, batch, scsh, pooled);
    k_head<<<(N_GRAPHS + 255) / 256, blk, 0, stream>>>(pooled, Wf1, bf1, Wf2, bf2, (float*)d_out);
}

// Round 5
// 1070.627 us; speedup vs baseline: 2.5720x; 1.1093x over previous
//
#include <hip/hip_runtime.h>

#define N_NODES 100000
#define N_EDGES 400000
#define N_GRAPHS 4096
#define BN_EPS 1e-5f
#define DEG_CAP 96

typedef unsigned short ushort_t;
typedef short short8 __attribute__((ext_vector_type(8)));
typedef unsigned short ushort4v __attribute__((ext_vector_type(4)));
typedef float floatx4 __attribute__((ext_vector_type(4)));

__device__ __forceinline__ ushort_t f2b(float f) {
    union { float f; unsigned u; } v; v.f = f;
    unsigned r = v.u + 0x7fffu + ((v.u >> 16) & 1u);
    return (ushort_t)(r >> 16);
}
__device__ __forceinline__ float b2f(ushort_t b) {
    union { unsigned u; float f; } v; v.u = ((unsigned)b) << 16;
    return v.f;
}

// ---------------- pad + convert x: [N][373] f32 -> [N][384] bf16 ----------------
// rows of x are only 4B-aligned (373 floats) -> scalar dword loads, short4 stores
__global__ void k_pad_x(const float* __restrict__ x, ushort_t* __restrict__ xb) {
    int n = blockIdx.x;
    int t = threadIdx.x;   // 128
    const float* xr = x + (long)n * 373;
    ushort_t* o = xb + (long)n * 384;
    if (t < 93) {
        float v0 = xr[t * 4 + 0], v1 = xr[t * 4 + 1], v2 = xr[t * 4 + 2], v3 = xr[t * 4 + 3];
        ushort4v s = {f2b(v0), f2b(v1), f2b(v2), f2b(v3)};
        *(ushort4v*)(o + t * 4) = s;
    } else if (t == 93) {
        o[372] = f2b(xr[372]);
        o[373] = 0; o[374] = 0; o[375] = 0;
    } else if (t == 94 || t == 95) {
        ushort4v z = {0, 0, 0, 0};
        *(ushort4v*)(o + 376 + (t - 94) * 4) = z;
    }
}

// ---------------- utility ----------------
__global__ void k_zero_int(int* __restrict__ p, int n) {
    int i = blockIdx.x * blockDim.x + threadIdx.x;
    if (i < n) p[i] = 0;
}
__global__ void k_zero_f32(float* __restrict__ p, int n) {
    int i = blockIdx.x * blockDim.x + threadIdx.x;
    if (i < n) p[i] = 0.f;
}

// ---------------- bucketed in-edge lists ----------------
__global__ void k_fill(const int* __restrict__ src, const int* __restrict__ dst,
                       int* __restrict__ cursor, int* __restrict__ elist) {
    int e = blockIdx.x * blockDim.x + threadIdx.x;
    if (e < N_EDGES) {
        int d = dst[e];
        int slot = atomicAdd(&cursor[d], 1);
        if (slot < DEG_CAP) elist[(long)d * DEG_CAP + slot] = src[e];
    }
}

// ---------------- weight prep: BT[n][k] = bf16(W[k][n] * sc[k]), K-padded ----------------
__global__ void k_prep_bt(const float* __restrict__ W, const float* __restrict__ sc,
                          ushort_t* __restrict__ BT, int K, int Kp, int Nn) {
    int k = blockIdx.x * 128 + threadIdx.x;
    int n = blockIdx.y;
    if (k >= Kp) return;
    float v = 0.f;
    if (k < K) { v = W[(long)k * Nn + n]; if (sc) v *= sc[k]; }
    BT[(long)n * Kp + k] = f2b(v);
}

// biasEff[n] = sum_k sh[k] * W[k][n]
__global__ void k_bias_eff(const float* __restrict__ W, const float* __restrict__ sh,
                           float* __restrict__ out, int K, int Nn) {
    int n = blockIdx.x * blockDim.x + threadIdx.x;
    if (n >= Nn) return;
    float s = 0.f;
    for (int k = 0; k < K; k++) s += sh[k] * W[(long)k * Nn + n];
    out[n] = s;
}

// ---------------- MFMA GEMM, LDS-free: C[M][Nn] = epi(A[M][KP] @ BT^T) ----------------
// 256 threads = 4 waves; wave w owns rows [block*128 + w*32, +32) x all 64 block-cols.
// A and B fragments loaded direct global->VGPR (b128). No barriers anywhere.
template<int KP>
__global__ __launch_bounds__(256) void k_gemm(const ushort_t* __restrict__ A,
                                              const ushort_t* __restrict__ BT,
                                              const float* __restrict__ bias,
                                              ushort_t* __restrict__ C,
                                              int M, int Nn, int relu) {
    const int tid = threadIdx.x;
    const int wave = tid >> 6, lane = tid & 63;
    const int ln = lane & 15, kg = lane >> 4;
    const long rowBase = (long)blockIdx.x * 128;
    const int colBase = blockIdx.y * 64;

    long r0 = rowBase + wave * 32 + ln;      // mt=0 row for this lane
    long r1 = r0 + 16;                       // mt=1 row
    if (r0 >= M) r0 = M - 1;
    if (r1 >= M) r1 = M - 1;
    const ushort_t* a0 = A + r0 * KP + kg * 8;
    const ushort_t* a1 = A + r1 * KP + kg * 8;
    const ushort_t* bp = BT + (long)(colBase + ln) * KP + kg * 8;

    floatx4 acc[2][4];
#pragma unroll
    for (int i = 0; i < 2; i++)
#pragma unroll
        for (int j = 0; j < 4; j++) acc[i][j] = (floatx4){0.f, 0.f, 0.f, 0.f};

#pragma unroll 2
    for (int k0 = 0; k0 < KP; k0 += 32) {
        short8 af0 = *(const short8*)(a0 + k0);
        short8 af1 = *(const short8*)(a1 + k0);
        short8 bfr[4];
#pragma unroll
        for (int tn = 0; tn < 4; tn++)
            bfr[tn] = *(const short8*)(bp + (long)tn * 16 * KP + k0);
#pragma unroll
        for (int tn = 0; tn < 4; tn++)
            acc[0][tn] = __builtin_amdgcn_mfma_f32_16x16x32_bf16(af0, bfr[tn], acc[0][tn], 0, 0, 0);
#pragma unroll
        for (int tn = 0; tn < 4; tn++)
            acc[1][tn] = __builtin_amdgcn_mfma_f32_16x16x32_bf16(af1, bfr[tn], acc[1][tn], 0, 0, 0);
    }

    // epilogue: 16x16 C/D layout: col = lane&15, row = (lane>>4)*4 + reg
#pragma unroll
    for (int mt = 0; mt < 2; mt++) {
#pragma unroll
        for (int tn = 0; tn < 4; tn++) {
            int gc = colBase + tn * 16 + ln;
            float bv = bias ? bias[gc] : 0.f;
#pragma unroll
            for (int r = 0; r < 4; r++) {
                long gr = rowBase + wave * 32 + mt * 16 + kg * 4 + r;
                if (gr < M) {
                    float v = acc[mt][tn][r] + bv;
                    if (relu) v = fmaxf(v, 0.f);
                    C[gr * Nn + gc] = f2b(v);
                }
            }
        }
    }
}

// ---------------- gather-aggregate: out[n] = relu(y[n] + sum_nbr y[s] + badd) ----------
// 64-thread blocks; each thread handles 4 channels (ushort4); 256/D nodes per block.
template<int D>
__global__ void k_aggregate(const ushort_t* __restrict__ y, const int* __restrict__ cursor,
                            const int* __restrict__ elist, const float* __restrict__ badd,
                            ushort_t* __restrict__ out) {
    const int CG = D / 4;                 // threads per node
    const int NPB = 64 / CG;              // nodes per block
    int t = threadIdx.x;
    int n = blockIdx.x * NPB + t / CG;
    int c = (t % CG) * 4;
    if (n >= N_NODES) return;
    int cnt = cursor[n];
    if (cnt > DEG_CAP) cnt = DEG_CAP;
    ushort4v sv = *(const ushort4v*)(y + (long)n * D + c);
    float t0 = b2f(sv.x), t1 = b2f(sv.y), t2 = b2f(sv.z), t3 = b2f(sv.w);
    const int* el = elist + (long)n * DEG_CAP;
    for (int i = 0; i < cnt; i++) {
        long s = el[i];
        ushort4v v = *(const ushort4v*)(y + s * D + c);
        t0 += b2f(v.x); t1 += b2f(v.y); t2 += b2f(v.z); t3 += b2f(v.w);
    }
    t0 = fmaxf(t0 + badd[c + 0], 0.f);
    t1 = fmaxf(t1 + badd[c + 1], 0.f);
    t2 = fmaxf(t2 + badd[c + 2], 0.f);
    t3 = fmaxf(t3 + badd[c + 3], 0.f);
    ushort4v o = {f2b(t0), f2b(t1), f2b(t2), f2b(t3)};
    *(ushort4v*)(out + (long)n * D + c) = o;
}

// ---------------- BatchNorm stats ----------------
__global__ void k_bn_accum(const ushort_t* __restrict__ h, float* __restrict__ stats, int N, int K) {
    int tid = threadIdx.x;
    int c = tid & (K - 1);
    int rpb = blockDim.x / K;
    int rowOff = tid / K;
    float s = 0.f, s2 = 0.f;
    for (int r = blockIdx.x * rpb + rowOff; r < N; r += gridDim.x * rpb) {
        float v = b2f(h[(long)r * K + c]);
        s += v; s2 += v * v;
    }
    atomicAdd(&stats[c], s);
    atomicAdd(&stats[K + c], s2);
}

__global__ void k_bn_finalize(const float* __restrict__ stats, const float* __restrict__ gamma,
                              const float* __restrict__ beta, float* __restrict__ scsh, int K) {
    int c = threadIdx.x;
    if (c < K) {
        float invN = 1.0f / (float)N_NODES;
        float mu = stats[c] * invN;
        float var = fmaxf(stats[K + c] * invN - mu * mu, 0.f);
        float sc = rsqrtf(var + BN_EPS) * gamma[c];
        scsh[c] = sc;
        scsh[K + c] = beta[c] - mu * sc;
    }
}

// ---------------- segmented pool (batch sorted): block = graph, 64 threads ----------------
__global__ void k_pool(const ushort_t* __restrict__ h, const int* __restrict__ batch,
                       const float* __restrict__ scsh, float* __restrict__ pooled) {
    int g = blockIdx.x;
    int c = threadIdx.x;
    int lo = 0, hi = N_NODES;
    while (lo < hi) { int mid = (lo + hi) >> 1; if (batch[mid] < g) lo = mid + 1; else hi = mid; }
    int start = lo;
    hi = N_NODES;
    while (lo < hi) { int mid = (lo + hi) >> 1; if (batch[mid] < g + 1) lo = mid + 1; else hi = mid; }
    int end = lo;
    float s = 0.f;
    for (int r = start; r < end; r++) s += b2f(h[(long)r * 64 + c]);
    pooled[g * 64 + c] = s * scsh[c] + scsh[64 + c] * (float)(end - start);
}

// ---------------- head ----------------
__global__ void k_head(const float* __restrict__ pooled, const float* __restrict__ Wf1,
                       const float* __restrict__ bf1, const float* __restrict__ Wf2,
                       const float* __restrict__ bf2, float* __restrict__ out) {
    int g = blockIdx.x * blockDim.x + threadIdx.x;
    if (g >= N_GRAPHS) return;
    const float* p = pooled + g * 64;
    float o = 0.f;
#pragma unroll
    for (int k = 0; k < 16; k++) {
        float s = bf1[k];
        for (int c = 0; c < 64; c++) s += p[c] * Wf1[c * 16 + k];
        s = fmaxf(s, 0.f);
        o += s * Wf2[k];
    }
    o += bf2[0];
    o = fmaxf(o, 0.f);
    out[g] = o;
}

// ---------------- launch ----------------
extern "C" void kernel_launch(void* const* d_in, const int* in_sizes, int n_in,
                              void* d_out, int out_size, void* d_ws, size_t ws_size,
                              hipStream_t stream) {
    const float* x    = (const float*)d_in[0];
    const int*  ei    = (const int*)d_in[1];
    const int*  batch = (const int*)d_in[2];
    const float* W1a = (const float*)d_in[3];
    const float* b1a = (const float*)d_in[4];
    const float* W1b = (const float*)d_in[5];
    const float* b1b = (const float*)d_in[6];
    const float* g1  = (const float*)d_in[7];
    const float* be1 = (const float*)d_in[8];
    const float* W2a = (const float*)d_in[9];
    const float* b2a = (const float*)d_in[10];
    const float* W2b = (const float*)d_in[11];
    const float* b2b = (const float*)d_in[12];
    const float* g2  = (const float*)d_in[13];
    const float* be2 = (const float*)d_in[14];
    const float* W3a = (const float*)d_in[15];
    const float* b3a = (const float*)d_in[16];
    const float* W3b = (const float*)d_in[17];
    const float* b3b = (const float*)d_in[18];
    const float* g3  = (const float*)d_in[19];
    const float* be3 = (const float*)d_in[20];
    const float* Wf1 = (const float*)d_in[21];
    const float* bf1 = (const float*)d_in[22];
    const float* Wf2 = (const float*)d_in[23];
    const float* bf2 = (const float*)d_in[24];

    const int N = N_NODES, E = N_EDGES;
    const int* src = ei;
    const int* dst = ei + E;

    // ---- workspace carve (256B aligned) ----
    char* wp = (char*)d_ws;
    auto carve = [&](size_t bytes) {
        char* p = wp;
        wp += (bytes + 255) & ~(size_t)255;
        return (void*)p;
    };
    ushort_t* xb     = (ushort_t*)carve((size_t)N * 384 * 2);
    ushort_t* bufA   = (ushort_t*)carve((size_t)N * 256 * 2);
    ushort_t* bufB   = (ushort_t*)carve((size_t)N * 256 * 2);
    int*      elist  = (int*)carve((size_t)N * DEG_CAP * 4);
    int*      cursor = (int*)carve((size_t)N * 4);
    ushort_t* BT     = (ushort_t*)carve((size_t)256 * 384 * 2);
    float*    stats  = (float*)carve(512 * 4);
    float*    scsh   = (float*)carve(512 * 4);
    float*    biasE  = (float*)carve(256 * 4);
    float*    pooled = (float*)carve((size_t)N_GRAPHS * 64 * 4);

    dim3 blk(256);
    const int gx = (N + 127) / 128;   // 782

    // ---- prep: pad x, build in-edge buckets ----
    k_pad_x<<<N, 128, 0, stream>>>(x, xb);
    k_zero_int<<<(N + 255) / 256, blk, 0, stream>>>(cursor, N);
    k_fill<<<(E + 255) / 256, blk, 0, stream>>>(src, dst, cursor, elist);

    // ---------- layer 1: 373 -> 256 -> 256 ----------
    k_prep_bt<<<dim3(3, 256), 128, 0, stream>>>(W1a, nullptr, BT, 373, 384, 256);
    k_gemm<384><<<dim3(gx, 4), blk, 0, stream>>>(xb, BT, nullptr, bufA, N, 256, 0);
    k_aggregate<256><<<N, 64, 0, stream>>>(bufA, cursor, elist, b1a, bufB);
    k_prep_bt<<<dim3(2, 256), 128, 0, stream>>>(W1b, nullptr, BT, 256, 256, 256);
    k_gemm<256><<<dim3(gx, 4), blk, 0, stream>>>(bufB, BT, b1b, bufA, N, 256, 1);
    k_zero_f32<<<2, blk, 0, stream>>>(stats, 512);
    k_bn_accum<<<256, blk, 0, stream>>>(bufA, stats, N, 256);
    k_bn_finalize<<<1, blk, 0, stream>>>(stats, g1, be1, scsh, 256);

    // ---------- layer 2: 256 -> 128 -> 128 (BN folded into W2a + biasEff) ----------
    k_prep_bt<<<dim3(2, 128), 128, 0, stream>>>(W2a, scsh, BT, 256, 256, 128);
    k_bias_eff<<<1, 128, 0, stream>>>(W2a, scsh + 256, biasE, 256, 128);
    k_gemm<256><<<dim3(gx, 2), blk, 0, stream>>>(bufA, BT, biasE, bufB, N, 128, 0);
    k_aggregate<128><<<(N + 1) / 2, 64, 0, stream>>>(bufB, cursor, elist, b2a, bufA);
    k_prep_bt<<<dim3(1, 128), 128, 0, stream>>>(W2b, nullptr, BT, 128, 128, 128);
    k_gemm<128><<<dim3(gx, 2), blk, 0, stream>>>(bufA, BT, b2b, bufB, N, 128, 1);
    k_zero_f32<<<2, blk, 0, stream>>>(stats, 512);
    k_bn_accum<<<256, blk, 0, stream>>>(bufB, stats, N, 128);
    k_bn_finalize<<<1, blk, 0, stream>>>(stats, g2, be2, scsh, 128);

    // ---------- layer 3: 128 -> 64 -> 64 ----------
    k_prep_bt<<<dim3(1, 64), 128, 0, stream>>>(W3a, scsh, BT, 128, 128, 64);
    k_bias_eff<<<1, 64, 0, stream>>>(W3a, scsh + 128, biasE, 128, 64);
    k_gemm<128><<<dim3(gx, 1), blk, 0, stream>>>(bufB, BT, biasE, bufA, N, 64, 0);
    k_aggregate<64><<<(N + 3) / 4, 64, 0, stream>>>(bufA, cursor, elist, b3a, bufB);
    k_prep_bt<<<dim3(1, 64), 128, 0, stream>>>(W3b, nullptr, BT, 64, 64, 64);
    k_gemm<64><<<dim3(gx, 1), blk, 0, stream>>>(bufB, BT, b3b, bufA, N, 64, 1);
    k_zero_f32<<<2, blk, 0, stream>>>(stats, 512);
    k_bn_accum<<<256, blk, 0, stream>>>(bufA, stats, N, 64);
    k_bn_finalize<<<1, blk, 0, stream>>>(stats, g3, be3, scsh, 64);

    // ---------- pool (segmented, BN affine fused) + head ----------
    k_pool<<<N_GRAPHS, 64, 0, stream>>>(bufA, batch, scsh, pooled);
    k_head<<<(N_GRAPHS + 255) / 256, blk, 0, stream>>>(pooled, Wf1, bf1, Wf2, bf2, (float*)d_out);
}

// Round 6
// 947.954 us; speedup vs baseline: 2.9048x; 1.1294x over previous
//
#include <hip/hip_runtime.h>

#define N_NODES 100000
#define N_EDGES 400000
#define N_GRAPHS 4096
#define BN_EPS 1e-5f
#define DEG_CAP 96

typedef unsigned short ushort_t;
typedef short short8 __attribute__((ext_vector_type(8)));
typedef unsigned short ushort4v __attribute__((ext_vector_type(4)));
typedef float floatx4 __attribute__((ext_vector_type(4)));

__device__ __forceinline__ ushort_t f2b(float f) {
    union { float f; unsigned u; } v; v.f = f;
    unsigned r = v.u + 0x7fffu + ((v.u >> 16) & 1u);
    return (ushort_t)(r >> 16);
}
__device__ __forceinline__ float b2f(ushort_t b) {
    union { unsigned u; float f; } v; v.u = ((unsigned)b) << 16;
    return v.f;
}

// ---------------- pad + convert x: [N][373] f32 -> [N][384] bf16 ----------------
__global__ void k_pad_x(const float* __restrict__ x, ushort_t* __restrict__ xb) {
    int n = blockIdx.x;
    int t = threadIdx.x;   // 128
    const float* xr = x + (long)n * 373;
    ushort_t* o = xb + (long)n * 384;
    if (t < 93) {
        float v0 = xr[t * 4 + 0], v1 = xr[t * 4 + 1], v2 = xr[t * 4 + 2], v3 = xr[t * 4 + 3];
        ushort4v s = {f2b(v0), f2b(v1), f2b(v2), f2b(v3)};
        *(ushort4v*)(o + t * 4) = s;
    } else if (t == 93) {
        o[372] = f2b(xr[372]);
        o[373] = 0; o[374] = 0; o[375] = 0;
    } else if (t == 94 || t == 95) {
        ushort4v z = {0, 0, 0, 0};
        *(ushort4v*)(o + 376 + (t - 94) * 4) = z;
    }
}

// ---------------- utility ----------------
__global__ void k_zero_int(int* __restrict__ p, int n) {
    int i = blockIdx.x * blockDim.x + threadIdx.x;
    if (i < n) p[i] = 0;
}
__global__ void k_zero_f32(float* __restrict__ p, int n) {
    int i = blockIdx.x * blockDim.x + threadIdx.x;
    if (i < n) p[i] = 0.f;
}

// ---------------- bucketed in-edge lists ----------------
__global__ void k_fill(const int* __restrict__ src, const int* __restrict__ dst,
                       int* __restrict__ cursor, int* __restrict__ elist) {
    int e = blockIdx.x * blockDim.x + threadIdx.x;
    if (e < N_EDGES) {
        int d = dst[e];
        int slot = atomicAdd(&cursor[d], 1);
        if (slot < DEG_CAP) elist[(long)d * DEG_CAP + slot] = src[e];
    }
}

// ---------------- weight prep: BT[n][k] = bf16(W[k][n] * sc[k]), K-padded ----------------
__global__ void k_prep_bt(const float* __restrict__ W, const float* __restrict__ sc,
                          ushort_t* __restrict__ BT, int K, int Kp, int Nn) {
    int k = blockIdx.x * 128 + threadIdx.x;
    int n = blockIdx.y;
    if (k >= Kp) return;
    float v = 0.f;
    if (k < K) { v = W[(long)k * Nn + n]; if (sc) v *= sc[k]; }
    BT[(long)n * Kp + k] = f2b(v);
}

// biasEff[n] = sum_k sh[k] * W[k][n]
__global__ void k_bias_eff(const float* __restrict__ W, const float* __restrict__ sh,
                           float* __restrict__ out, int K, int Nn) {
    int n = blockIdx.x * blockDim.x + threadIdx.x;
    if (n >= Nn) return;
    float s = 0.f;
    for (int k = 0; k < K; k++) s += sh[k] * W[(long)k * Nn + n];
    out[n] = s;
}

// ---------------- MFMA GEMM, m97-style: C[M][Nn] = epi(A[M][KP] @ BT^T) ----------------
// Block: 128 rows x TN cols, 256 threads (4 waves).
// TN=128: waves in 2x2, each 64 rows x 64 cols (4x4 of 16x16 MFMA tiles).
// TN=64:  waves in 4x1, each 32 rows x 64 cols (2x4 tiles).
// Per 32-K step: stage A[128x32] + B[TN x 32] via global_load_lds (full-line),
// fragments via ds_read_b128, MFMAs with 2x register reuse.
template<int KP, int TN>
__global__ __launch_bounds__(256) void k_gemm(const ushort_t* __restrict__ A,
                                              const ushort_t* __restrict__ BT,
                                              const float* __restrict__ bias,
                                              ushort_t* __restrict__ C,
                                              int M, int Nn, int relu) {
    __shared__ __align__(16) ushort_t As[128 * 32];     // 8 KB, row-major [row][32k]
    __shared__ __align__(16) ushort_t Bs[TN * 32];      // 8/4 KB, [col][32k]
    const int tid = threadIdx.x;
    const int wave = tid >> 6, lane = tid & 63;
    const int ln = lane & 15, kg = lane >> 4;
    const long rowBase = (long)blockIdx.y * 128;
    const int colBase = blockIdx.x * TN;

    constexpr int RT = (TN == 128) ? 4 : 2;             // row-tiles per wave
    const int rowOff = (TN == 128) ? ((wave >> 1) * 64) : (wave * 32);
    const int colOff = (TN == 128) ? ((wave & 1) * 64) : 0;

    // --- staging source pointers (per-thread) ---
    // A instr i (i=0,1): row = rowBase + i*64 + tid/4, 16B chunk tid%4
    const ushort_t* aSrc[2];
#pragma unroll
    for (int i = 0; i < 2; i++) {
        long r = rowBase + i * 64 + (tid >> 2);
        if (r >= M) r = M - 1;
        aSrc[i] = A + r * KP + (tid & 3) * 8;
    }
    // B: TN/64 instrs: col = colBase + i*64 + tid/4
    const ushort_t* bSrc[TN / 64];
#pragma unroll
    for (int i = 0; i < TN / 64; i++) {
        long cc = colBase + i * 64 + (tid >> 2);
        bSrc[i] = BT + cc * KP + (tid & 3) * 8;
    }
    // LDS destinations (wave-uniform base; HW adds lane*16)
    ushort_t* aDst = As + wave * 512;                   // +i*2048 elems per instr
    ushort_t* bDst = Bs + wave * 512;

    floatx4 acc[RT][4];
#pragma unroll
    for (int i = 0; i < RT; i++)
#pragma unroll
        for (int j = 0; j < 4; j++) acc[i][j] = (floatx4){0.f, 0.f, 0.f, 0.f};

    for (int k0 = 0; k0 < KP; k0 += 32) {
        __syncthreads();
#pragma unroll
        for (int i = 0; i < 2; i++)
            __builtin_amdgcn_global_load_lds(
                (const __attribute__((address_space(1))) void*)(aSrc[i] + k0),
                (__attribute__((address_space(3))) void*)(aDst + i * 2048), 16, 0, 0);
#pragma unroll
        for (int i = 0; i < TN / 64; i++)
            __builtin_amdgcn_global_load_lds(
                (const __attribute__((address_space(1))) void*)(bSrc[i] + k0),
                (__attribute__((address_space(3))) void*)(bDst + i * 2048), 16, 0, 0);
        __syncthreads();

        short8 afr[RT], bfr[4];
#pragma unroll
        for (int rt = 0; rt < RT; rt++)
            afr[rt] = *(const short8*)&As[(rowOff + rt * 16 + ln) * 32 + kg * 8];
#pragma unroll
        for (int tn = 0; tn < 4; tn++)
            bfr[tn] = *(const short8*)&Bs[(colOff + tn * 16 + ln) * 32 + kg * 8];
#pragma unroll
        for (int rt = 0; rt < RT; rt++)
#pragma unroll
            for (int tn = 0; tn < 4; tn++)
                acc[rt][tn] = __builtin_amdgcn_mfma_f32_16x16x32_bf16(afr[rt], bfr[tn], acc[rt][tn], 0, 0, 0);
    }

    // epilogue: 16x16 C/D layout: col = lane&15, row = (lane>>4)*4 + reg
#pragma unroll
    for (int rt = 0; rt < RT; rt++) {
#pragma unroll
        for (int tn = 0; tn < 4; tn++) {
            int gc = colBase + colOff + tn * 16 + ln;
            float bv = bias ? bias[gc] : 0.f;
#pragma unroll
            for (int r = 0; r < 4; r++) {
                long gr = rowBase + rowOff + rt * 16 + kg * 4 + r;
                if (gr < M) {
                    float v = acc[rt][tn][r] + bv;
                    if (relu) v = fmaxf(v, 0.f);
                    C[gr * Nn + gc] = f2b(v);
                }
            }
        }
    }
}

// ---------------- gather-aggregate: out[n] = relu(y[n] + sum_nbr y[s] + badd) ----------
template<int D>
__global__ void k_aggregate(const ushort_t* __restrict__ y, const int* __restrict__ cursor,
                            const int* __restrict__ elist, const float* __restrict__ badd,
                            ushort_t* __restrict__ out) {
    const int CG = D / 4;                 // threads per node
    const int NPB = 64 / CG;              // nodes per block
    int t = threadIdx.x;
    int n = blockIdx.x * NPB + t / CG;
    int c = (t % CG) * 4;
    if (n >= N_NODES) return;
    int cnt = cursor[n];
    if (cnt > DEG_CAP) cnt = DEG_CAP;
    ushort4v sv = *(const ushort4v*)(y + (long)n * D + c);
    float t0 = b2f(sv.x), t1 = b2f(sv.y), t2 = b2f(sv.z), t3 = b2f(sv.w);
    const int* el = elist + (long)n * DEG_CAP;
    if (cnt > 0) {
        long s0 = el[0];
        ushort4v nv = *(const ushort4v*)(y + s0 * D + c);
        for (int i = 1; i <= cnt; i++) {
            ushort4v cur = nv;
            if (i < cnt) {
                long s = el[i];
                nv = *(const ushort4v*)(y + s * D + c);
            }
            t0 += b2f(cur.x); t1 += b2f(cur.y); t2 += b2f(cur.z); t3 += b2f(cur.w);
        }
    }
    t0 = fmaxf(t0 + badd[c + 0], 0.f);
    t1 = fmaxf(t1 + badd[c + 1], 0.f);
    t2 = fmaxf(t2 + badd[c + 2], 0.f);
    t3 = fmaxf(t3 + badd[c + 3], 0.f);
    ushort4v o = {f2b(t0), f2b(t1), f2b(t2), f2b(t3)};
    *(ushort4v*)(out + (long)n * D + c) = o;
}

// ---------------- BatchNorm stats ----------------
__global__ void k_bn_accum(const ushort_t* __restrict__ h, float* __restrict__ stats, int N, int K) {
    int tid = threadIdx.x;
    int c = tid & (K - 1);
    int rpb = blockDim.x / K;
    int rowOff = tid / K;
    float s = 0.f, s2 = 0.f;
    for (int r = blockIdx.x * rpb + rowOff; r < N; r += gridDim.x * rpb) {
        float v = b2f(h[(long)r * K + c]);
        s += v; s2 += v * v;
    }
    atomicAdd(&stats[c], s);
    atomicAdd(&stats[K + c], s2);
}

__global__ void k_bn_finalize(const float* __restrict__ stats, const float* __restrict__ gamma,
                              const float* __restrict__ beta, float* __restrict__ scsh, int K) {
    int c = threadIdx.x;
    if (c < K) {
        float invN = 1.0f / (float)N_NODES;
        float mu = stats[c] * invN;
        float var = fmaxf(stats[K + c] * invN - mu * mu, 0.f);
        float sc = rsqrtf(var + BN_EPS) * gamma[c];
        scsh[c] = sc;
        scsh[K + c] = beta[c] - mu * sc;
    }
}

// ---------------- segmented pool (batch sorted): block = graph, 64 threads ----------------
__global__ void k_pool(const ushort_t* __restrict__ h, const int* __restrict__ batch,
                       const float* __restrict__ scsh, float* __restrict__ pooled) {
    int g = blockIdx.x;
    int c = threadIdx.x;
    int lo = 0, hi = N_NODES;
    while (lo < hi) { int mid = (lo + hi) >> 1; if (batch[mid] < g) lo = mid + 1; else hi = mid; }
    int start = lo;
    hi = N_NODES;
    while (lo < hi) { int mid = (lo + hi) >> 1; if (batch[mid] < g + 1) lo = mid + 1; else hi = mid; }
    int end = lo;
    float s = 0.f;
    for (int r = start; r < end; r++) s += b2f(h[(long)r * 64 + c]);
    pooled[g * 64 + c] = s * scsh[c] + scsh[64 + c] * (float)(end - start);
}

// ---------------- head ----------------
__global__ void k_head(const float* __restrict__ pooled, const float* __restrict__ Wf1,
                       const float* __restrict__ bf1, const float* __restrict__ Wf2,
                       const float* __restrict__ bf2, float* __restrict__ out) {
    int g = blockIdx.x * blockDim.x + threadIdx.x;
    if (g >= N_GRAPHS) return;
    const float* p = pooled + g * 64;
    float o = 0.f;
#pragma unroll
    for (int k = 0; k < 16; k++) {
        float s = bf1[k];
        for (int c = 0; c < 64; c++) s += p[c] * Wf1[c * 16 + k];
        s = fmaxf(s, 0.f);
        o += s * Wf2[k];
    }
    o += bf2[0];
    o = fmaxf(o, 0.f);
    out[g] = o;
}

// ---------------- launch ----------------
extern "C" void kernel_launch(void* const* d_in, const int* in_sizes, int n_in,
                              void* d_out, int out_size, void* d_ws, size_t ws_size,
                              hipStream_t stream) {
    const float* x    = (const float*)d_in[0];
    const int*  ei    = (const int*)d_in[1];
    const int*  batch = (const int*)d_in[2];
    const float* W1a = (const float*)d_in[3];
    const float* b1a = (const float*)d_in[4];
    const float* W1b = (const float*)d_in[5];
    const float* b1b = (const float*)d_in[6];
    const float* g1  = (const float*)d_in[7];
    const float* be1 = (const float*)d_in[8];
    const float* W2a = (const float*)d_in[9];
    const float* b2a = (const float*)d_in[10];
    const float* W2b = (const float*)d_in[11];
    const float* b2b = (const float*)d_in[12];
    const float* g2  = (const float*)d_in[13];
    const float* be2 = (const float*)d_in[14];
    const float* W3a = (const float*)d_in[15];
    const float* b3a = (const float*)d_in[16];
    const float* W3b = (const float*)d_in[17];
    const float* b3b = (const float*)d_in[18];
    const float* g3  = (const float*)d_in[19];
    const float* be3 = (const float*)d_in[20];
    const float* Wf1 = (const float*)d_in[21];
    const float* bf1 = (const float*)d_in[22];
    const float* Wf2 = (const float*)d_in[23];
    const float* bf2 = (const float*)d_in[24];

    const int N = N_NODES, E = N_EDGES;
    const int* src = ei;
    const int* dst = ei + E;

    // ---- workspace carve (256B aligned) ----
    char* wp = (char*)d_ws;
    auto carve = [&](size_t bytes) {
        char* p = wp;
        wp += (bytes + 255) & ~(size_t)255;
        return (void*)p;
    };
    ushort_t* xb     = (ushort_t*)carve((size_t)N * 384 * 2);
    ushort_t* bufA   = (ushort_t*)carve((size_t)N * 256 * 2);
    ushort_t* bufB   = (ushort_t*)carve((size_t)N * 256 * 2);
    int*      elist  = (int*)carve((size_t)N * DEG_CAP * 4);
    int*      cursor = (int*)carve((size_t)N * 4);
    ushort_t* BT     = (ushort_t*)carve((size_t)256 * 384 * 2);
    float*    stats  = (float*)carve(1536 * 4);          // 3 layers x 512
    float*    scsh   = (float*)carve(512 * 4);
    float*    biasE  = (float*)carve(256 * 4);
    float*    pooled = (float*)carve((size_t)N_GRAPHS * 64 * 4);

    dim3 blk(256);
    const int gy = (N + 127) / 128;   // 782 row-tiles

    // ---- prep: pad x, build in-edge buckets, zero all BN stats ----
    k_pad_x<<<N, 128, 0, stream>>>(x, xb);
    k_zero_int<<<(N + 255) / 256, blk, 0, stream>>>(cursor, N);
    k_zero_f32<<<6, blk, 0, stream>>>(stats, 1536);
    k_fill<<<(E + 255) / 256, blk, 0, stream>>>(src, dst, cursor, elist);

    // ---------- layer 1: 373 -> 256 -> 256 ----------
    k_prep_bt<<<dim3(3, 256), 128, 0, stream>>>(W1a, nullptr, BT, 373, 384, 256);
    k_gemm<384, 128><<<dim3(2, gy), blk, 0, stream>>>(xb, BT, nullptr, bufA, N, 256, 0);
    k_aggregate<256><<<N, 64, 0, stream>>>(bufA, cursor, elist, b1a, bufB);
    k_prep_bt<<<dim3(2, 256), 128, 0, stream>>>(W1b, nullptr, BT, 256, 256, 256);
    k_gemm<256, 128><<<dim3(2, gy), blk, 0, stream>>>(bufB, BT, b1b, bufA, N, 256, 1);
    k_bn_accum<<<256, blk, 0, stream>>>(bufA, stats, N, 256);
    k_bn_finalize<<<1, blk, 0, stream>>>(stats, g1, be1, scsh, 256);

    // ---------- layer 2: 256 -> 128 -> 128 (BN folded into W2a + biasEff) ----------
    k_prep_bt<<<dim3(2, 128), 128, 0, stream>>>(W2a, scsh, BT, 256, 256, 128);
    k_bias_eff<<<1, 128, 0, stream>>>(W2a, scsh + 256, biasE, 256, 128);
    k_gemm<256, 128><<<dim3(1, gy), blk, 0, stream>>>(bufA, BT, biasE, bufB, N, 128, 0);
    k_aggregate<128><<<(N + 1) / 2, 64, 0, stream>>>(bufB, cursor, elist, b2a, bufA);
    k_prep_bt<<<dim3(1, 128), 128, 0, stream>>>(W2b, nullptr, BT, 128, 128, 128);
    k_gemm<128, 128><<<dim3(1, gy), blk, 0, stream>>>(bufA, BT, b2b, bufB, N, 128, 1);
    k_bn_accum<<<256, blk, 0, stream>>>(bufB, stats + 512, N, 128);
    k_bn_finalize<<<1, blk, 0, stream>>>(stats + 512, g2, be2, scsh, 128);

    // ---------- layer 3: 128 -> 64 -> 64 ----------
    k_prep_bt<<<dim3(1, 64), 128, 0, stream>>>(W3a, scsh, BT, 128, 128, 64);
    k_bias_eff<<<1, 64, 0, stream>>>(W3a, scsh + 128, biasE, 128, 64);
    k_gemm<128, 64><<<dim3(1, gy), blk, 0, stream>>>(bufB, BT, biasE, bufA, N, 64, 0);
    k_aggregate<64><<<(N + 3) / 4, 64, 0, stream>>>(bufA, cursor, elist, b3a, bufB);
    k_prep_bt<<<dim3(1, 64), 128, 0, stream>>>(W3b, nullptr, BT, 64, 64, 64);
    k_gemm<64, 64><<<dim3(1, gy), blk, 0, stream>>>(bufB, BT, b3b, bufA, N, 64, 1);
    k_bn_accum<<<256, blk, 0, stream>>>(bufA, stats + 1024, N, 64);
    k_bn_finalize<<<1, blk, 0, stream>>>(stats + 1024, g3, be3, scsh, 64);

    // ---------- pool (segmented, BN affine fused) + head ----------
    k_pool<<<N_GRAPHS, 64, 0, stream>>>(bufA, batch, scsh, pooled);
    k_head<<<(N_GRAPHS + 255) / 256, blk, 0, stream>>>(pooled, Wf1, bf1, Wf2, bf2, (float*)d_out);
}

// Round 7
// 871.500 us; speedup vs baseline: 3.1597x; 1.0877x over previous
//
#include <hip/hip_runtime.h>

#define N_NODES 100000
#define N_EDGES 400000
#define N_GRAPHS 4096
#define BN_EPS 1e-5f
#define DEG_CAP 96

typedef unsigned short ushort_t;
typedef short short8 __attribute__((ext_vector_type(8)));
typedef unsigned short ushort4v __attribute__((ext_vector_type(4)));
typedef float floatx4 __attribute__((ext_vector_type(4)));

__device__ __forceinline__ ushort_t f2b(float f) {
    union { float f; unsigned u; } v; v.f = f;
    unsigned r = v.u + 0x7fffu + ((v.u >> 16) & 1u);
    return (ushort_t)(r >> 16);
}
__device__ __forceinline__ float b2f(ushort_t b) {
    union { unsigned u; float f; } v; v.u = ((unsigned)b) << 16;
    return v.f;
}

// ---------------- pad + convert x: [N][373] f32 -> [N][384] bf16 ----------------
__global__ void k_pad_x(const float* __restrict__ x, ushort_t* __restrict__ xb) {
    int n = blockIdx.x;
    int t = threadIdx.x;   // 128
    const float* xr = x + (long)n * 373;
    ushort_t* o = xb + (long)n * 384;
    if (t < 93) {
        float v0 = xr[t * 4 + 0], v1 = xr[t * 4 + 1], v2 = xr[t * 4 + 2], v3 = xr[t * 4 + 3];
        ushort4v s = {f2b(v0), f2b(v1), f2b(v2), f2b(v3)};
        *(ushort4v*)(o + t * 4) = s;
    } else if (t == 93) {
        o[372] = f2b(xr[372]);
        o[373] = 0; o[374] = 0; o[375] = 0;
    } else if (t == 94 || t == 95) {
        ushort4v z = {0, 0, 0, 0};
        *(ushort4v*)(o + 376 + (t - 94) * 4) = z;
    }
}

// ---------------- utility ----------------
__global__ void k_zero_int(int* __restrict__ p, int n) {
    int i = blockIdx.x * blockDim.x + threadIdx.x;
    if (i < n) p[i] = 0;
}
__global__ void k_zero_f32(float* __restrict__ p, int n) {
    int i = blockIdx.x * blockDim.x + threadIdx.x;
    if (i < n) p[i] = 0.f;
}

// ---------------- bucketed in-edge lists ----------------
__global__ void k_fill(const int* __restrict__ src, const int* __restrict__ dst,
                       int* __restrict__ cursor, int* __restrict__ elist) {
    int e = blockIdx.x * blockDim.x + threadIdx.x;
    if (e < N_EDGES) {
        int d = dst[e];
        int slot = atomicAdd(&cursor[d], 1);
        if (slot < DEG_CAP) elist[(long)d * DEG_CAP + slot] = src[e];
    }
}

// ---------------- weight prep: BT[n][k] = bf16(W[k][n] * sc[k]), K-padded ----------------
__global__ void k_prep_bt(const float* __restrict__ W, const float* __restrict__ sc,
                          ushort_t* __restrict__ BT, int K, int Kp, int Nn) {
    int k = blockIdx.x * 128 + threadIdx.x;
    int n = blockIdx.y;
    if (k >= Kp) return;
    float v = 0.f;
    if (k < K) { v = W[(long)k * Nn + n]; if (sc) v *= sc[k]; }
    BT[(long)n * Kp + k] = f2b(v);
}

// biasEff[n] = sum_k sh[k] * W[k][n]
__global__ void k_bias_eff(const float* __restrict__ W, const float* __restrict__ sh,
                           float* __restrict__ out, int K, int Nn) {
    int n = blockIdx.x * blockDim.x + threadIdx.x;
    if (n >= Nn) return;
    float s = 0.f;
    for (int k = 0; k < K; k++) s += sh[k] * W[(long)k * Nn + n];
    out[n] = s;
}

// ---------------- MFMA GEMM, m97-style, optional fused BN-stats ----------------
// Block: 128 rows x TN cols, 256 threads (4 waves).
// TN=128: waves 2x2, each 64r x 64c (4x4 MFMA tiles). TN=64: waves 4x1, 32r x 64c.
// Per 32-K step: stage A[128x32]+B[TNx32] via global_load_lds, ds_read_b128 frags.
// STATS: epilogue accumulates per-column sum/sumsq of the stored (rounded) values
// into stats[0..Nn) / stats[Nn..2Nn) via shuffle-reduce + atomics.
template<int KP, int TN, bool STATS>
__global__ __launch_bounds__(256) void k_gemm(const ushort_t* __restrict__ A,
                                              const ushort_t* __restrict__ BT,
                                              const float* __restrict__ bias,
                                              ushort_t* __restrict__ C,
                                              float* __restrict__ stats,
                                              int M, int Nn, int relu) {
    __shared__ __align__(16) ushort_t As[128 * 32];     // 8 KB
    __shared__ __align__(16) ushort_t Bs[TN * 32];      // 8/4 KB
    const int tid = threadIdx.x;
    const int wave = tid >> 6, lane = tid & 63;
    const int ln = lane & 15, kg = lane >> 4;
    const long rowBase = (long)blockIdx.y * 128;
    const int colBase = blockIdx.x * TN;

    constexpr int RT = (TN == 128) ? 4 : 2;
    const int rowOff = (TN == 128) ? ((wave >> 1) * 64) : (wave * 32);
    const int colOff = (TN == 128) ? ((wave & 1) * 64) : 0;

    const ushort_t* aSrc[2];
#pragma unroll
    for (int i = 0; i < 2; i++) {
        long r = rowBase + i * 64 + (tid >> 2);
        if (r >= M) r = M - 1;
        aSrc[i] = A + r * KP + (tid & 3) * 8;
    }
    const ushort_t* bSrc[TN / 64];
#pragma unroll
    for (int i = 0; i < TN / 64; i++) {
        long cc = colBase + i * 64 + (tid >> 2);
        bSrc[i] = BT + cc * KP + (tid & 3) * 8;
    }
    ushort_t* aDst = As + wave * 512;
    ushort_t* bDst = Bs + wave * 512;

    floatx4 acc[RT][4];
#pragma unroll
    for (int i = 0; i < RT; i++)
#pragma unroll
        for (int j = 0; j < 4; j++) acc[i][j] = (floatx4){0.f, 0.f, 0.f, 0.f};

    for (int k0 = 0; k0 < KP; k0 += 32) {
        __syncthreads();
#pragma unroll
        for (int i = 0; i < 2; i++)
            __builtin_amdgcn_global_load_lds(
                (const __attribute__((address_space(1))) void*)(aSrc[i] + k0),
                (__attribute__((address_space(3))) void*)(aDst + i * 2048), 16, 0, 0);
#pragma unroll
        for (int i = 0; i < TN / 64; i++)
            __builtin_amdgcn_global_load_lds(
                (const __attribute__((address_space(1))) void*)(bSrc[i] + k0),
                (__attribute__((address_space(3))) void*)(bDst + i * 2048), 16, 0, 0);
        __syncthreads();

        short8 afr[RT], bfr[4];
#pragma unroll
        for (int rt = 0; rt < RT; rt++)
            afr[rt] = *(const short8*)&As[(rowOff + rt * 16 + ln) * 32 + kg * 8];
#pragma unroll
        for (int tn = 0; tn < 4; tn++)
            bfr[tn] = *(const short8*)&Bs[(colOff + tn * 16 + ln) * 32 + kg * 8];
#pragma unroll
        for (int rt = 0; rt < RT; rt++)
#pragma unroll
            for (int tn = 0; tn < 4; tn++)
                acc[rt][tn] = __builtin_amdgcn_mfma_f32_16x16x32_bf16(afr[rt], bfr[tn], acc[rt][tn], 0, 0, 0);
    }

    // epilogue: 16x16 C/D layout: col = lane&15, row = (lane>>4)*4 + reg
    float sums[4] = {0.f, 0.f, 0.f, 0.f};
    float sqs[4]  = {0.f, 0.f, 0.f, 0.f};
#pragma unroll
    for (int rt = 0; rt < RT; rt++) {
#pragma unroll
        for (int tn = 0; tn < 4; tn++) {
            int gc = colBase + colOff + tn * 16 + ln;
            float bv = bias ? bias[gc] : 0.f;
#pragma unroll
            for (int r = 0; r < 4; r++) {
                long gr = rowBase + rowOff + rt * 16 + kg * 4 + r;
                if (gr < M) {
                    float v = acc[rt][tn][r] + bv;
                    if (relu) v = fmaxf(v, 0.f);
                    ushort_t sb = f2b(v);
                    C[gr * Nn + gc] = sb;
                    if (STATS) {
                        float vb = b2f(sb);
                        sums[tn] += vb;
                        sqs[tn] += vb * vb;
                    }
                }
            }
        }
    }
    if (STATS) {
#pragma unroll
        for (int tn = 0; tn < 4; tn++) {
            float s = sums[tn], q = sqs[tn];
            s += __shfl_xor(s, 16); q += __shfl_xor(q, 16);
            s += __shfl_xor(s, 32); q += __shfl_xor(q, 32);
            if (kg == 0) {
                int gc = colBase + colOff + tn * 16 + ln;
                atomicAdd(&stats[gc], s);
                atomicAdd(&stats[Nn + gc], q);
            }
        }
    }
}

// ---------------- gather-aggregate: out[n] = relu(y[n] + sum_nbr y[s] + badd) ----------
template<int D>
__global__ void k_aggregate(const ushort_t* __restrict__ y, const int* __restrict__ cursor,
                            const int* __restrict__ elist, const float* __restrict__ badd,
                            ushort_t* __restrict__ out) {
    const int CG = D / 4;
    const int NPB = 64 / CG;
    int t = threadIdx.x;
    int n = blockIdx.x * NPB + t / CG;
    int c = (t % CG) * 4;
    if (n >= N_NODES) return;
    int cnt = cursor[n];
    if (cnt > DEG_CAP) cnt = DEG_CAP;
    ushort4v sv = *(const ushort4v*)(y + (long)n * D + c);
    float t0 = b2f(sv.x), t1 = b2f(sv.y), t2 = b2f(sv.z), t3 = b2f(sv.w);
    const int* el = elist + (long)n * DEG_CAP;
    if (cnt > 0) {
        long s0 = el[0];
        ushort4v nv = *(const ushort4v*)(y + s0 * D + c);
        for (int i = 1; i <= cnt; i++) {
            ushort4v cur = nv;
            if (i < cnt) {
                long s = el[i];
                nv = *(const ushort4v*)(y + s * D + c);
            }
            t0 += b2f(cur.x); t1 += b2f(cur.y); t2 += b2f(cur.z); t3 += b2f(cur.w);
        }
    }
    t0 = fmaxf(t0 + badd[c + 0], 0.f);
    t1 = fmaxf(t1 + badd[c + 1], 0.f);
    t2 = fmaxf(t2 + badd[c + 2], 0.f);
    t3 = fmaxf(t3 + badd[c + 3], 0.f);
    ushort4v o = {f2b(t0), f2b(t1), f2b(t2), f2b(t3)};
    *(ushort4v*)(out + (long)n * D + c) = o;
}

// ---------------- BN finalize ----------------
__global__ void k_bn_finalize(const float* __restrict__ stats, const float* __restrict__ gamma,
                              const float* __restrict__ beta, float* __restrict__ scsh, int K) {
    int c = threadIdx.x;
    if (c < K) {
        float invN = 1.0f / (float)N_NODES;
        float mu = stats[c] * invN;
        float var = fmaxf(stats[K + c] * invN - mu * mu, 0.f);
        float sc = rsqrtf(var + BN_EPS) * gamma[c];
        scsh[c] = sc;
        scsh[K + c] = beta[c] - mu * sc;
    }
}

// ---------------- segmented pool (batch sorted): block = graph, 64 threads ----------------
__global__ void k_pool(const ushort_t* __restrict__ h, const int* __restrict__ batch,
                       const float* __restrict__ scsh, float* __restrict__ pooled) {
    int g = blockIdx.x;
    int c = threadIdx.x;
    int lo = 0, hi = N_NODES;
    while (lo < hi) { int mid = (lo + hi) >> 1; if (batch[mid] < g) lo = mid + 1; else hi = mid; }
    int start = lo;
    hi = N_NODES;
    while (lo < hi) { int mid = (lo + hi) >> 1; if (batch[mid] < g + 1) lo = mid + 1; else hi = mid; }
    int end = lo;
    float s = 0.f;
    for (int r = start; r < end; r++) s += b2f(h[(long)r * 64 + c]);
    pooled[g * 64 + c] = s * scsh[c] + scsh[64 + c] * (float)(end - start);
}

// ---------------- head ----------------
__global__ void k_head(const float* __restrict__ pooled, const float* __restrict__ Wf1,
                       const float* __restrict__ bf1, const float* __restrict__ Wf2,
                       const float* __restrict__ bf2, float* __restrict__ out) {
    int g = blockIdx.x * blockDim.x + threadIdx.x;
    if (g >= N_GRAPHS) return;
    const float* p = pooled + g * 64;
    float o = 0.f;
#pragma unroll
    for (int k = 0; k < 16; k++) {
        float s = bf1[k];
        for (int c = 0; c < 64; c++) s += p[c] * Wf1[c * 16 + k];
        s = fmaxf(s, 0.f);
        o += s * Wf2[k];
    }
    o += bf2[0];
    o = fmaxf(o, 0.f);
    out[g] = o;
}

// ---------------- launch ----------------
extern "C" void kernel_launch(void* const* d_in, const int* in_sizes, int n_in,
                              void* d_out, int out_size, void* d_ws, size_t ws_size,
                              hipStream_t stream) {
    const float* x    = (const float*)d_in[0];
    const int*  ei    = (const int*)d_in[1];
    const int*  batch = (const int*)d_in[2];
    const float* W1a = (const float*)d_in[3];
    const float* b1a = (const float*)d_in[4];
    const float* W1b = (const float*)d_in[5];
    const float* b1b = (const float*)d_in[6];
    const float* g1  = (const float*)d_in[7];
    const float* be1 = (const float*)d_in[8];
    const float* W2a = (const float*)d_in[9];
    const float* b2a = (const float*)d_in[10];
    const float* W2b = (const float*)d_in[11];
    const float* b2b = (const float*)d_in[12];
    const float* g2  = (const float*)d_in[13];
    const float* be2 = (const float*)d_in[14];
    const float* W3a = (const float*)d_in[15];
    const float* b3a = (const float*)d_in[16];
    const float* W3b = (const float*)d_in[17];
    const float* b3b = (const float*)d_in[18];
    const float* g3  = (const float*)d_in[19];
    const float* be3 = (const float*)d_in[20];
    const float* Wf1 = (const float*)d_in[21];
    const float* bf1 = (const float*)d_in[22];
    const float* Wf2 = (const float*)d_in[23];
    const float* bf2 = (const float*)d_in[24];

    const int N = N_NODES, E = N_EDGES;
    const int* src = ei;
    const int* dst = ei + E;

    // ---- workspace carve (256B aligned) ----
    char* wp = (char*)d_ws;
    auto carve = [&](size_t bytes) {
        char* p = wp;
        wp += (bytes + 255) & ~(size_t)255;
        return (void*)p;
    };
    ushort_t* xb     = (ushort_t*)carve((size_t)N * 384 * 2);
    ushort_t* bufA   = (ushort_t*)carve((size_t)N * 256 * 2);
    ushort_t* bufB   = (ushort_t*)carve((size_t)N * 256 * 2);
    int*      elist  = (int*)carve((size_t)N * DEG_CAP * 4);
    int*      cursor = (int*)carve((size_t)N * 4);
    ushort_t* BT     = (ushort_t*)carve((size_t)256 * 384 * 2);
    float*    stats  = (float*)carve(1536 * 4);          // 3 layers x 512
    float*    scsh   = (float*)carve(512 * 4);
    float*    biasE  = (float*)carve(256 * 4);
    float*    pooled = (float*)carve((size_t)N_GRAPHS * 64 * 4);

    dim3 blk(256);
    const int gy = (N + 127) / 128;   // 782 row-tiles

    // ---- prep: pad x, zero stats/cursor, build in-edge buckets ----
    k_pad_x<<<N, 128, 0, stream>>>(x, xb);
    k_zero_int<<<(N + 255) / 256, blk, 0, stream>>>(cursor, N);
    k_zero_f32<<<6, blk, 0, stream>>>(stats, 1536);
    k_fill<<<(E + 255) / 256, blk, 0, stream>>>(src, dst, cursor, elist);

    // ---------- layer 1: 373 -> 256 -> 256 ----------
    k_prep_bt<<<dim3(3, 256), 128, 0, stream>>>(W1a, nullptr, BT, 373, 384, 256);
    k_gemm<384, 128, false><<<dim3(2, gy), blk, 0, stream>>>(xb, BT, nullptr, bufA, nullptr, N, 256, 0);
    k_aggregate<256><<<N, 64, 0, stream>>>(bufA, cursor, elist, b1a, bufB);
    k_prep_bt<<<dim3(2, 256), 128, 0, stream>>>(W1b, nullptr, BT, 256, 256, 256);
    k_gemm<256, 128, true><<<dim3(2, gy), blk, 0, stream>>>(bufB, BT, b1b, bufA, stats, N, 256, 1);
    k_bn_finalize<<<1, blk, 0, stream>>>(stats, g1, be1, scsh, 256);

    // ---------- layer 2: 256 -> 128 -> 128 (BN folded into W2a + biasEff) ----------
    k_prep_bt<<<dim3(2, 128), 128, 0, stream>>>(W2a, scsh, BT, 256, 256, 128);
    k_bias_eff<<<1, 128, 0, stream>>>(W2a, scsh + 256, biasE, 256, 128);
    k_gemm<256, 128, false><<<dim3(1, gy), blk, 0, stream>>>(bufA, BT, biasE, bufB, nullptr, N, 128, 0);
    k_aggregate<128><<<(N + 1) / 2, 64, 0, stream>>>(bufB, cursor, elist, b2a, bufA);
    k_prep_bt<<<dim3(1, 128), 128, 0, stream>>>(W2b, nullptr, BT, 128, 128, 128);
    k_gemm<128, 128, true><<<dim3(1, gy), blk, 0, stream>>>(bufA, BT, b2b, bufB, stats + 512, N, 128, 1);
    k_bn_finalize<<<1, blk, 0, stream>>>(stats + 512, g2, be2, scsh, 128);

    // ---------- layer 3: 128 -> 64 -> 64 ----------
    k_prep_bt<<<dim3(1, 64), 128, 0, stream>>>(W3a, scsh, BT, 128, 128, 64);
    k_bias_eff<<<1, 64, 0, stream>>>(W3a, scsh + 128, biasE, 128, 64);
    k_gemm<128, 64, false><<<dim3(1, gy), blk, 0, stream>>>(bufB, BT, biasE, bufA, nullptr, N, 64, 0);
    k_aggregate<64><<<(N + 3) / 4, 64, 0, stream>>>(bufA, cursor, elist, b3a, bufB);
    k_prep_bt<<<dim3(1, 64), 128, 0, stream>>>(W3b, nullptr, BT, 64, 64, 64);
    k_gemm<64, 64, true><<<dim3(1, gy), blk, 0, stream>>>(bufB, BT, b3b, bufA, stats + 1024, N, 64, 1);
    k_bn_finalize<<<1, blk, 0, stream>>>(stats + 1024, g3, be3, scsh, 64);

    // ---------- pool (segmented, BN affine fused) + head ----------
    k_pool<<<N_GRAPHS, 64, 0, stream>>>(bufA, batch, scsh, pooled);
    k_head<<<(N_GRAPHS + 255) / 256, blk, 0, stream>>>(pooled, Wf1, bf1, Wf2, bf2, (float*)d_out);
}